// Round 10
// baseline (253.029 us; speedup 1.0000x reference)
//
#include <hip/hip_runtime.h>
#include <math.h>

#define T_TOKENS 16384
#define D_DIM    2048
#define E_EXP    64
#define TOPK     8
#define NS       4                   // K slices (across waves; interleaved per phase)
#define PH       8                   // K phases
#define PKC      256                 // k per phase (1 KB per token row)
#define TT       32                  // tokens per block (2 blocks/CU)
#define TOKP     36                  // token stride in epilogue slab (16B-aligned rows)

typedef __attribute__((ext_vector_type(8))) short bf16x8;
typedef __attribute__((ext_vector_type(4))) float f32x4;

__device__ __forceinline__ unsigned short bf16rne(float f) {
  unsigned u = __builtin_bit_cast(unsigned, f);
  unsigned r = u + 0x7fffu + ((u >> 16) & 1u);
  return (unsigned short)(r >> 16);
}
__device__ __forceinline__ float bf16f(unsigned short h) {
  return __builtin_bit_cast(float, (unsigned)h << 16);
}

// async global->LDS, 16 B per lane; LDS dest wave-uniform base + lane*16.
__device__ __forceinline__ void gload16(const void* g, void* l) {
  __builtin_amdgcn_global_load_lds(
      (const __attribute__((address_space(1))) unsigned int*)g,
      (__attribute__((address_space(3))) unsigned int*)l,
      16, 0, 0);
}

// ---------------- Probe: in-harness ideal READ-stream reference ----------------
// Measures the achievable read bandwidth under the harness's real cache state
// (512 MiB poison written every iteration). 2048 blocks x 256 thr, grid-stride
// float4, 16 independent loads/thread (m13 pattern: 1 KB contiguous per wave
// instruction, deep MLP, no barriers, 8 blocks/CU). Reads 128 MiB of the
// WORKSPACE (same size as x; poisoned-earliest region => HBM/L3-dirty, the
// worst case the fused kernel faces) so it does NOT warm x in L3 — the fused
// kernel's conditions stay identical to R9 for clean Delta-total attribution.
__global__ __launch_bounds__(256) void probe_stream_kernel(
    const float* __restrict__ src, float* __restrict__ dst)
{
  const int gid = blockIdx.x * 256 + threadIdx.x;     // 0..524287
  const f32x4* p = (const f32x4*)src;
  f32x4 a = (f32x4){0.f, 0.f, 0.f, 0.f};
  #pragma unroll
  for (int i = 0; i < 16; ++i) {
    f32x4 v = p[(size_t)i * 524288 + gid];            // 8388608 float4 = 128 MiB
    a[0] += v[0]; a[1] += v[1]; a[2] += v[2]; a[3] += v[3];
  }
  dst[gid] = a[0] + a[1] + a[2] + a[3];               // keep loads live (2 MB, dead region)
}

// ---------------- Kernel 0: pre-convert gate_w to frag-ordered bf16 hi/lo ----
// entry id = ((c*4 + kq)*64 + e): c = k/32 chunk, kq = k-quad, e = expert.
// Entry = 8 bf16 (16 B) = g[e][c*32 + kq*8 .. +7]. Also zeroes counts region.
__global__ __launch_bounds__(256) void convert_g_kernel(
    const float* __restrict__ gw, unsigned short* __restrict__ ph,
    unsigned short* __restrict__ pl, float* __restrict__ counts_zero)
{
  const int id = blockIdx.x * 256 + threadIdx.x;   // 0..16383
  if (blockIdx.x == 0 && threadIdx.x < E_EXP) counts_zero[threadIdx.x] = 0.0f;

  const int e  = id & 63;
  const int kq = (id >> 6) & 3;
  const int c  = id >> 8;
  const float* gp = &gw[(size_t)e * D_DIM + c * 32 + kq * 8];
  float4 v0 = *(const float4*)&gp[0];
  float4 v1 = *(const float4*)&gp[4];
  const float xs[8] = {v0.x, v0.y, v0.z, v0.w, v1.x, v1.y, v1.z, v1.w};
  bf16x8 hi, lo;
  #pragma unroll
  for (int j = 0; j < 8; ++j) {
    unsigned short h = bf16rne(xs[j]);
    hi[j] = (short)h;
    lo[j] = (short)bf16rne(xs[j] - bf16f(h));
  }
  *(bf16x8*)&ph[(size_t)id * 8] = hi;
  *(bf16x8*)&pl[(size_t)id * 8] = lo;
}

// ---------------- Kernel 1 (fused): logits + reduce + top-8 + counts ----------
// BYTE-IDENTICAL to R9 (contiguous gload16 staging, dbuf, B-before-stage,
// R5 epilogue). Kept frozen this round so Delta-total isolates the probe.
__global__ __launch_bounds__(512, 4) void moe_fused_kernel(
    const float* __restrict__ x, const unsigned short* __restrict__ ph,
    const unsigned short* __restrict__ pl, const float* __restrict__ bias,
    float* __restrict__ out)
{
  __shared__ char smem[65536];    // A dbuf 2 x 32 KB; epilogue slab alias
  __shared__ unsigned hist[E_EXP];

  const int tid  = threadIdx.x;
  const int wave = tid >> 6;
  const int lane = tid & 63;
  const int l15  = lane & 15;
  const int quad = lane >> 4;
  const int wg   = wave & 1;          // token group (0..1)
  const int wsl  = wave >> 1;         // K slice (0..3)
  const int tok0 = blockIdx.x * TT;

  // ---- staging: wave stages rows wave*4 .. wave*4+3; 1 instruction = 1 row ----
  const int srow = wave * 4;
  const float* gS[4];
  #pragma unroll
  for (int i = 0; i < 4; ++i) {
    const int row = srow + i;
    gS[i] = &x[(size_t)(tok0 + row) * D_DIM + (size_t)(lane ^ (row & 7)) * 4];
  }

#define STAGE(p, buf)                                                      \
  {                                                                        \
    gload16(gS[0] + (size_t)(p) * PKC, (void*)(smem + (buf) * 32768 + (srow + 0) * 1024)); \
    gload16(gS[1] + (size_t)(p) * PKC, (void*)(smem + (buf) * 32768 + (srow + 1) * 1024)); \
    gload16(gS[2] + (size_t)(p) * PKC, (void*)(smem + (buf) * 32768 + (srow + 2) * 1024)); \
    gload16(gS[3] + (size_t)(p) * PKC, (void*)(smem + (buf) * 32768 + (srow + 3) * 1024)); \
  }

  // B frag bases (frag-packed bf16 hi/lo; chunk cg stride 2048 shorts)
  const unsigned short* bh0 = ph + quad * 512 + l15 * 8;
  const unsigned short* bl0 = pl + quad * 512 + l15 * 8;

  f32x4 acc[4];
  #pragma unroll
  for (int et = 0; et < 4; ++et) acc[et] = (f32x4){0.f, 0.f, 0.f, 0.f};

  const int swk = l15 & 7;            // read-side swizzle key (row&7 = l15&7)

  STAGE(0, 0);
  __syncthreads();   // phase 0 resident

  int buf = 0;
  #pragma unroll 1
  for (int p = 0; p < PH; ++p) {
    // ---- B for both 32-k sub-chunks (issue BEFORE the stage) ----
    bf16x8 bh[2][4], bl[2][4];
    #pragma unroll
    for (int sub = 0; sub < 2; ++sub) {
      const size_t cg = (size_t)(p * 8 + wsl * 2 + sub) * 2048;
      #pragma unroll
      for (int et = 0; et < 4; ++et) {
        bh[sub][et] = *(const bf16x8*)&bh0[cg + et * 128];
        bl[sub][et] = *(const bf16x8*)&bl0[cg + et * 128];
      }
    }

    // ---- issue next phase's A stage (in flight across the whole phase) ----
    if (p + 1 < PH) STAGE(p + 1, buf ^ 1);

    const float* ab = (const float*)(smem + buf * 32768) + (wg * 16 + l15) * 256;

    #pragma unroll
    for (int sub = 0; sub < 2; ++sub) {
      // ---- A-frag from LDS: row wg*16+l15, logical slots s0,s0+1 (swizzled) ----
      const int s0 = wsl * 16 + sub * 8 + quad * 2;
      f32x4 a0 = *(const f32x4*)&ab[((s0    ) ^ swk) * 4];
      f32x4 a1 = *(const f32x4*)&ab[((s0 + 1) ^ swk) * 4];

      // ---- split A to hi/lo bf16 (register-only; numerics unchanged) ----
      const float xs[8] = {a0[0], a0[1], a0[2], a0[3], a1[0], a1[1], a1[2], a1[3]};
      bf16x8 ah, al;
      #pragma unroll
      for (int j = 0; j < 8; ++j) {
        unsigned short h = bf16rne(xs[j]);
        ah[j] = (short)h;
        al[j] = (short)bf16rne(xs[j] - bf16f(h));
      }

      // ---- 12 MFMAs ----
      #pragma unroll
      for (int et = 0; et < 4; ++et) {
        acc[et] = __builtin_amdgcn_mfma_f32_16x16x32_bf16(ah, bh[sub][et], acc[et], 0, 0, 0);
        acc[et] = __builtin_amdgcn_mfma_f32_16x16x32_bf16(al, bh[sub][et], acc[et], 0, 0, 0);
        acc[et] = __builtin_amdgcn_mfma_f32_16x16x32_bf16(ah, bl[sub][et], acc[et], 0, 0, 0);
      }
    }

    __syncthreads();   // drains the (already-progressed) stage; swap buffers
    buf ^= 1;
  }

  // ---- epilogue (R5 verbatim; slab aliases the staging buffers) ----
  float* slab = (float*)smem;                // NS*E_EXP*TOKP floats = 36864 B

  // acc -> slab: D row(m)=quad*4+r (token), col(n)=et*16+l15 (expert)
  #pragma unroll
  for (int et = 0; et < 4; ++et) {
    *(f32x4*)&slab[((size_t)(wsl * E_EXP + et * 16 + l15)) * TOKP + wg * 16 + quad * 4] = acc[et];
  }
  if (tid < E_EXP) hist[tid] = 0;
  __syncthreads();

  // reduce 4 slices + bias into slice 0 (512 thr x f32x4 = 64 experts x 32 tokens).
  // Summation order: bias, +s0..+s3 (matches prior passing versions).
  {
    const int e  = tid >> 3;          // 0..63
    const int t4 = (tid & 7) * 4;     // 0..28
    f32x4 s0 = *(const f32x4*)&slab[(size_t)(0 * E_EXP + e) * TOKP + t4];
    f32x4 s1 = *(const f32x4*)&slab[(size_t)(1 * E_EXP + e) * TOKP + t4];
    f32x4 s2 = *(const f32x4*)&slab[(size_t)(2 * E_EXP + e) * TOKP + t4];
    f32x4 s3 = *(const f32x4*)&slab[(size_t)(3 * E_EXP + e) * TOKP + t4];
    const float b = bias[e];
    f32x4 v;
    #pragma unroll
    for (int j = 0; j < 4; ++j) v[j] = (((b + s0[j]) + s1[j]) + s2[j]) + s3[j];
    *(f32x4*)&slab[(size_t)(0 * E_EXP + e) * TOKP + t4] = v;
  }
  __syncthreads();

  if (tid >= 64) return;   // waves 1..7 done; wave 0 finishes the 32 tokens

  if (tid < TT) {
    const int t = tid;
    float l[E_EXP];
    #pragma unroll
    for (int j = 0; j < E_EXP; ++j) l[j] = slab[(size_t)j * TOKP + t];

    float tv[TOPK]; int tix[TOPK];
    unsigned long long used = 0ull;
    #pragma unroll
    for (int k = 0; k < TOPK; ++k) {
      float best = -INFINITY; int bi = 0;
      #pragma unroll
      for (int j = 0; j < E_EXP; ++j) {
        bool ok = (((used >> j) & 1ull) == 0ull) && (l[j] > best);  // strict >: lowest index wins ties
        best = ok ? l[j] : best;
        bi   = ok ? j : bi;
      }
      tv[k] = best; tix[k] = bi;
      used |= (1ull << bi);
    }

    float m = tv[0], s = 0.0f, w[TOPK];
    #pragma unroll
    for (int k = 0; k < TOPK; ++k) { w[k] = expf(tv[k] - m); s += w[k]; }
    float inv = 1.0f / s;

    const size_t gt = (size_t)blockIdx.x * TT + t;
    #pragma unroll
    for (int k = 0; k < TOPK; ++k) {
      out[gt * TOPK + k] = (float)tix[k];                                // indices as fp32
      out[(size_t)T_TOKENS * TOPK + gt * TOPK + k] = w[k] * inv;         // weights
    }

    #pragma unroll
    for (int k = 0; k < TOPK; ++k) atomicAdd(&hist[tix[k]], 1u);
  }
  __threadfence_block();   // order wave-0's LDS atomics before its reads
  atomicAdd(&out[2 * (size_t)T_TOKENS * TOPK + tid], (float)hist[tid]);
}

extern "C" void kernel_launch(void* const* d_in, const int* in_sizes, int n_in,
                              void* d_out, int out_size, void* d_ws, size_t ws_size,
                              hipStream_t stream) {
  const float* x    = (const float*)d_in[0];
  const float* gw   = (const float*)d_in[1];
  const float* bias = (const float*)d_in[2];
  float* out  = (float*)d_out;

  // ws layout: ph (256 KB) | pl (256 KB) | ... | probe scratch (dead)
  unsigned short* ph = (unsigned short*)d_ws;
  unsigned short* pl = ph + (size_t)E_EXP * D_DIM;

  // ---- read-stream probe (measurement only; outputs unused) ----
  // Reads ws[0, 128 MiB); writes 2 MB of sums at ws + 240 MiB. Only if the
  // workspace is big enough (the harness poisons 512 MiB, so it is).
  if (ws_size >= ((size_t)256 << 20)) {
    float* scratch = (float*)((char*)d_ws + ((size_t)240 << 20));
    probe_stream_kernel<<<dim3(2048), dim3(256), 0, stream>>>(
        (const float*)d_ws, scratch);
  }

  convert_g_kernel<<<dim3(E_EXP * D_DIM / 8 / 256), dim3(256), 0, stream>>>(
      gw, ph, pl, out + 2 * (size_t)T_TOKENS * TOPK);
  moe_fused_kernel<<<dim3(T_TOKENS / TT), dim3(512), 0, stream>>>(
      x, ph, pl, bias, out);
}